// Round 1
// baseline (4960.302 us; speedup 1.0000x reference)
//
#include <hip/hip_runtime.h>

// GRU-D: nf=64 filters, B=128, T=100, I=64, H=128, C=2I+H=256
#define NF 64
#define BATCH 128
#define TT 100
#define II 64
#define HH 128
#define CC 256
#define BB 32          // batch rows per block
#define NTHR 512
#define PSTRIDE 111297

// param offsets (floats) from cumsum of _SIZES
#define OFF_ZW 0
#define OFF_ZB 32768
#define OFF_RW 32896
#define OFF_RB 65664
#define OFF_HW 65792
#define OFF_HB 98560
#define OFF_GXW 98688
#define OFF_GXB 102784
#define OFF_GHW 102848
#define OFF_GHB 111040
#define OFF_FCW 111168
#define OFF_FCB 111296

// ws layout (floats):
//   wzr2 [NF][CC][HH][2]  : (zwT[c][j], rwT[c][j])
//   wh2  [NF][CC][64][2]  : (hwT[c][jj], hwT[c][jj+64])
//   wgh2 [NF][II][64][2]  : (ghwT[i][jj], ghwT[i][jj+64])
#define WZR_SZ (64ull*256*128*2)
#define WH_OFF (WZR_SZ)
#define WH_SZ  (64ull*256*64*2)
#define WGH_OFF (WH_OFF + WH_SZ)
#define WGH_SZ (64ull*64*64*2)
#define WS_TOTAL (WGH_OFF + WGH_SZ)

__device__ __forceinline__ float sigmoidf_(float x) { return 1.f / (1.f + __expf(-x)); }

__global__ void repack_kernel(const float* __restrict__ p, float* __restrict__ ws) {
  for (size_t e = (size_t)blockIdx.x * 256 + threadIdx.x; e < WS_TOTAL;
       e += (size_t)gridDim.x * 256) {
    float v;
    if (e < WH_OFF) {
      size_t r = e; int s = (int)(r & 1); r >>= 1;
      int j = (int)(r & 127); r >>= 7;
      int c = (int)(r & 255); int n = (int)(r >> 8);
      v = p[(size_t)n * PSTRIDE + (s ? OFF_RW : OFF_ZW) + j * CC + c];
    } else if (e < WGH_OFF) {
      size_t r = e - WH_OFF; int s = (int)(r & 1); r >>= 1;
      int jj = (int)(r & 63); r >>= 6;
      int c = (int)(r & 255); int n = (int)(r >> 8);
      v = p[(size_t)n * PSTRIDE + OFF_HW + (jj + s * 64) * CC + c];
    } else {
      size_t r = e - WGH_OFF; int s = (int)(r & 1); r >>= 1;
      int jj = (int)(r & 63); r >>= 6;
      int i = (int)(r & 63); int n = (int)(r >> 6);
      v = p[(size_t)n * PSTRIDE + OFF_GHW + (jj + s * 64) * II + i];
    }
    ws[e] = v;
  }
}

// One block per (n, 32-batch chunk); persistent over all T steps.
// Thread map for matmul phases: jj = tid&63 -> outputs j in {jj, jj+64};
// (tid>>6) -> 4 batch rows. 2j x 4b = 8 outputs/thread per gate.
__global__ __launch_bounds__(NTHR, 1) void grud_main(
    const float* __restrict__ p, const float* __restrict__ X,
    const float* __restrict__ XL, const float* __restrict__ XM,
    const float* __restrict__ MK, const float* __restrict__ DE,
    const float* __restrict__ ws, float* __restrict__ out) {
  __shared__ float comb[BB][CC];     // [x(64) | h or r*h (128) | m(64)]
  __shared__ float hbuf[BB][HH];     // persistent h state
  __shared__ float dls[BB][II];      // staged delta

  const int tid = threadIdx.x;
  const int n = blockIdx.x & 63;     // same-n blocks land on same XCD (64%8==0)
  const int b0 = (blockIdx.x >> 6) * BB;
  const size_t pn = (size_t)n * PSTRIDE;
  const float* __restrict__ wzr = ws + (size_t)n * (256 * 128 * 2);
  const float* __restrict__ wh  = ws + WH_OFF + (size_t)n * (256 * 64 * 2);
  const float* __restrict__ wgh = ws + WGH_OFF + (size_t)n * (64 * 64 * 2);

  const int jj = tid & 63;
  const int bbase = (tid >> 6) * 4;

  const float zb0 = p[pn + OFF_ZB + jj], zb1 = p[pn + OFF_ZB + 64 + jj];
  const float rb0 = p[pn + OFF_RB + jj], rb1 = p[pn + OFF_RB + 64 + jj];
  const float hb0 = p[pn + OFF_HB + jj], hb1 = p[pn + OFF_HB + 64 + jj];
  const float gb0 = p[pn + OFF_GHB + jj], gb1 = p[pn + OFF_GHB + 64 + jj];

  for (int e = tid; e < BB * HH; e += NTHR) hbuf[e >> 7][e & 127] = 0.f;
  __syncthreads();

  for (int t = 0; t < TT; ++t) {
    // ---- Phase A: elementwise x, stage m/d ----
    #pragma unroll
    for (int q = 0; q < 4; ++q) {
      int e = q * NTHR + tid;
      int b = e >> 6, i = e & 63;
      size_t gb = ((size_t)(b0 + b) * TT + t) * II + i;
      size_t gn = (((size_t)n * BATCH + (b0 + b)) * TT + t) * II + i;
      float m = MK[gn], d = DE[gn];
      float dx = __expf(-fmaxf(fmaf(d, p[pn + OFF_GXW + i * 65], p[pn + OFF_GXB + i]), 0.f));
      float xv = m * X[gb] + (1.f - m) * (dx * XL[gb] + (1.f - dx) * XM[t * II + i]);
      comb[b][i] = xv;
      comb[b][192 + i] = m;
      dls[b][i] = d;
    }
    __syncthreads();

    // ---- Phase B: delta_h = exp(-relu(d@ghwT+ghb)); h *= delta_h ----
    {
      float a0[4] = {0, 0, 0, 0}, a1[4] = {0, 0, 0, 0};
      #pragma unroll 2
      for (int i = 0; i < II; i += 4) {
        float4 dv[4];
        #pragma unroll
        for (int bi = 0; bi < 4; bi++) dv[bi] = *(const float4*)&dls[bbase + bi][i];
        #pragma unroll
        for (int u = 0; u < 4; u++) {
          const float2 w = *(const float2*)&wgh[(size_t)((i + u) * 64 + jj) * 2];
          #pragma unroll
          for (int bi = 0; bi < 4; bi++) {
            float vv = (&dv[bi].x)[u];
            a0[bi] = fmaf(vv, w.x, a0[bi]);
            a1[bi] = fmaf(vv, w.y, a1[bi]);
          }
        }
      }
      #pragma unroll
      for (int bi = 0; bi < 4; bi++) {
        int b = bbase + bi;
        float dh0 = __expf(-fmaxf(a0[bi] + gb0, 0.f));
        float dh1 = __expf(-fmaxf(a1[bi] + gb1, 0.f));
        float h0 = hbuf[b][jj] * dh0;
        float h1 = hbuf[b][64 + jj] * dh1;
        hbuf[b][jj] = h0;       hbuf[b][64 + jj] = h1;
        comb[b][64 + jj] = h0;  comb[b][128 + jj] = h1;
      }
    }
    __syncthreads();

    // ---- Phase C1: z,r matmul over comb (256) ----
    float z0[4], z1[4], r0v[4], r1v[4];
    {
      float az0[4] = {0, 0, 0, 0}, az1[4] = {0, 0, 0, 0};
      float ar0[4] = {0, 0, 0, 0}, ar1[4] = {0, 0, 0, 0};
      #pragma unroll 2
      for (int c = 0; c < CC; c += 4) {
        float4 v[4];
        #pragma unroll
        for (int bi = 0; bi < 4; bi++) v[bi] = *(const float4*)&comb[bbase + bi][c];
        #pragma unroll
        for (int u = 0; u < 4; u++) {
          const float2 w0 = *(const float2*)&wzr[(size_t)((c + u) * 128 + jj) * 2];
          const float2 w1 = *(const float2*)&wzr[(size_t)((c + u) * 128 + 64 + jj) * 2];
          #pragma unroll
          for (int bi = 0; bi < 4; bi++) {
            float vv = (&v[bi].x)[u];
            az0[bi] = fmaf(vv, w0.x, az0[bi]);
            ar0[bi] = fmaf(vv, w0.y, ar0[bi]);
            az1[bi] = fmaf(vv, w1.x, az1[bi]);
            ar1[bi] = fmaf(vv, w1.y, ar1[bi]);
          }
        }
      }
      #pragma unroll
      for (int bi = 0; bi < 4; bi++) {
        z0[bi] = sigmoidf_(az0[bi] + zb0);
        z1[bi] = sigmoidf_(az1[bi] + zb1);
        r0v[bi] = sigmoidf_(ar0[bi] + rb0);
        r1v[bi] = sigmoidf_(ar1[bi] + rb1);
      }
    }
    __syncthreads();

    // ---- Phase C2: overwrite comb mid with r*h ----
    #pragma unroll
    for (int bi = 0; bi < 4; bi++) {
      int b = bbase + bi;
      comb[b][64 + jj] = r0v[bi] * hbuf[b][jj];
      comb[b][128 + jj] = r1v[bi] * hbuf[b][64 + jj];
    }
    __syncthreads();

    // ---- Phase D1: h_tilde matmul over comb (256) ----
    float ah0[4] = {0, 0, 0, 0}, ah1[4] = {0, 0, 0, 0};
    #pragma unroll 2
    for (int c = 0; c < CC; c += 4) {
      float4 v[4];
      #pragma unroll
      for (int bi = 0; bi < 4; bi++) v[bi] = *(const float4*)&comb[bbase + bi][c];
      #pragma unroll
      for (int u = 0; u < 4; u++) {
        const float2 w = *(const float2*)&wh[(size_t)((c + u) * 64 + jj) * 2];
        #pragma unroll
        for (int bi = 0; bi < 4; bi++) {
          float vv = (&v[bi].x)[u];
          ah0[bi] = fmaf(vv, w.x, ah0[bi]);
          ah1[bi] = fmaf(vv, w.y, ah1[bi]);
        }
      }
    }
    __syncthreads();

    // ---- Phase D2: h = (1-z)*h + z*tanh(ah + hb) ----
    #pragma unroll
    for (int bi = 0; bi < 4; bi++) {
      int b = bbase + bi;
      float ht0 = tanhf(ah0[bi] + hb0);
      float ht1 = tanhf(ah1[bi] + hb1);
      float h0 = hbuf[b][jj], h1 = hbuf[b][64 + jj];
      hbuf[b][jj] = (1.f - z0[bi]) * h0 + z0[bi] * ht0;
      hbuf[b][64 + jj] = (1.f - z1[bi]) * h1 + z1[bi] * ht1;
    }
    __syncthreads();
  }

  // ---- Final: out = sigmoid(h @ fcw + fcb) ----
  if (tid < BB) {
    float acc = 0.f;
    for (int j = 0; j < HH; ++j) acc = fmaf(hbuf[tid][j], p[pn + OFF_FCW + j], acc);
    out[(size_t)n * BATCH + b0 + tid] = sigmoidf_(acc + p[pn + OFF_FCB]);
  }
}

extern "C" void kernel_launch(void* const* d_in, const int* in_sizes, int n_in,
                              void* d_out, int out_size, void* d_ws, size_t ws_size,
                              hipStream_t stream) {
  const float* p  = (const float*)d_in[0];
  const float* X  = (const float*)d_in[1];
  const float* XL = (const float*)d_in[2];
  const float* XM = (const float*)d_in[3];
  const float* MK = (const float*)d_in[4];
  const float* DE = (const float*)d_in[5];
  float* out = (float*)d_out;
  float* ws = (float*)d_ws;
  if (ws_size < WS_TOTAL * sizeof(float)) return;  // need ~26 MB scratch

  hipLaunchKernelGGL(repack_kernel, dim3(4096), dim3(256), 0, stream, p, ws);
  hipLaunchKernelGGL(grud_main, dim3(NF * (BATCH / BB)), dim3(NTHR), 0, stream,
                     p, X, XL, XM, MK, DE, ws, out);
}

// Round 2
// 2694.318 us; speedup vs baseline: 1.8410x; 1.8410x over previous
//
#include <hip/hip_runtime.h>

// GRU-D: nf=64, B=128, T=100, I=64, H=128, C=256. MFMA 16x16x32 bf16, 3-term hi/lo.
#define NF 64
#define BATCH 128
#define TT 100
#define II 64
#define HH 128
#define CC 256
#define BB 32
#define NTHR 512
#define PSTRIDE 111297

#define OFF_ZW 0
#define OFF_ZB 32768
#define OFF_RW 32896
#define OFF_RB 65664
#define OFF_HW 65792
#define OFF_HB 98560
#define OFF_GXW 98688
#define OFF_GXB 102784
#define OFF_GHW 102848
#define OFF_GHB 111040
#define OFF_FCW 111168
#define OFF_FCB 111296

// ws layout (bf16 elems), per-lane MFMA B-fragment order:
//  frag addr = region + n*PER_N + (kt*NT + nt)*1024 + s*512 + l*8 + j   (s: 0=hi,1=lo)
#define ZR_PER_N 131072              // 8kt * 16nt * 2s * 512
#define H_BASE   (64 * ZR_PER_N)     // 8388608
#define H_PER_N  65536               // 8kt * 8nt * 2s * 512
#define G_BASE   (H_BASE + 64 * H_PER_N) // 12582912
#define G_PER_N  16384               // 2kt * 8nt * 2s * 512
#define WS_ELEMS (G_BASE + 64 * G_PER_N) // 13631488 bf16 = 26 MB

typedef __bf16 bf16x8 __attribute__((ext_vector_type(8)));
typedef __bf16 bf16x4 __attribute__((ext_vector_type(4)));
typedef float f32x4 __attribute__((ext_vector_type(4)));

__device__ __forceinline__ f32x4 mfma16(bf16x8 a, bf16x8 b, f32x4 c) {
  return __builtin_amdgcn_mfma_f32_16x16x32_bf16(a, b, c, 0, 0, 0);
}
__device__ __forceinline__ float sigmoidf_(float x) { return 1.f / (1.f + __expf(-x)); }

// ---- repack: params -> B-fragment-ordered bf16 hi/lo in ws ----
__global__ void repack_kernel(const float* __restrict__ p, __bf16* __restrict__ ws) {
  const int total = 4194304 + 2097152 + 524288;  // hi/lo pair tasks
  for (int e = blockIdx.x * 256 + threadIdx.x; e < total; e += gridDim.x * 256) {
    float wv; int dst;
    if (e < 4194304) {  // ZR: out = [z cols 0..127 | r cols 0..127], K=256
      int j = e & 7, l = (e >> 3) & 63, nt = (e >> 9) & 15, kt = (e >> 13) & 7, n = e >> 16;
      int c = kt * 32 + (l >> 4) * 8 + j, l15 = l & 15;
      long pn = (long)n * PSTRIDE;
      wv = (nt < 8) ? p[pn + OFF_ZW + (nt * 16 + l15) * CC + c]
                    : p[pn + OFF_RW + ((nt - 8) * 16 + l15) * CC + c];
      dst = n * ZR_PER_N + (kt * 16 + nt) * 1024 + l * 8 + j;
    } else if (e < 4194304 + 2097152) {  // H: h_tilde weights, K=256
      int e2 = e - 4194304;
      int j = e2 & 7, l = (e2 >> 3) & 63, nt = (e2 >> 9) & 7, kt = (e2 >> 12) & 7, n = e2 >> 15;
      int c = kt * 32 + (l >> 4) * 8 + j, l15 = l & 15;
      wv = p[(long)n * PSTRIDE + OFF_HW + (nt * 16 + l15) * CC + c];
      dst = H_BASE + n * H_PER_N + (kt * 8 + nt) * 1024 + l * 8 + j;
    } else {  // G: ghw [128][64], K=64
      int e2 = e - (4194304 + 2097152);
      int j = e2 & 7, l = (e2 >> 3) & 63, nt = (e2 >> 9) & 7, kt = (e2 >> 12) & 1, n = e2 >> 13;
      int c = kt * 32 + (l >> 4) * 8 + j, l15 = l & 15;
      wv = p[(long)n * PSTRIDE + OFF_GHW + (nt * 16 + l15) * II + c];
      dst = G_BASE + n * G_PER_N + (kt * 8 + nt) * 1024 + l * 8 + j;
    }
    __bf16 hi = (__bf16)wv;
    __bf16 lo = (__bf16)(wv - (float)hi);
    ws[dst] = hi;
    ws[dst + 512] = lo;
  }
}

// One block per (n, 32-batch chunk), persistent over T. 8 waves.
// Wave w: mt = w&1 (16-row batch tile), g = w>>1 (col group): cols c0=g*16+l15, c1=c0+64.
// h state lives in registers: h0[r],h1[r] at rows mt*16+lg*4+r, cols c0/c1 —
// identical C-frag ownership across delta_h / z / r / h_tilde phases.
__global__ __launch_bounds__(NTHR, 2) void grud_main(
    const float* __restrict__ p, const float* __restrict__ X,
    const float* __restrict__ XL, const float* __restrict__ XM,
    const float* __restrict__ MK, const float* __restrict__ DE,
    const __bf16* __restrict__ ws, float* __restrict__ out) {
  // A-fragment-layout LDS: [mt][kt][lane][8], lane = ((k>>3)&3)*16 + (row&15), j = k&7
  __shared__ __align__(16) __bf16 combA_hi[2][8][64][8];
  __shared__ __align__(16) __bf16 combA_lo[2][8][64][8];
  __shared__ __align__(16) __bf16 dls_hi[2][2][64][8];
  __shared__ __align__(16) __bf16 dls_lo[2][2][64][8];
  __shared__ float hstage[32][132];

  const int tid = threadIdx.x;
  const int w = tid >> 6, l = tid & 63;
  const int l15 = l & 15, lg = l >> 4;
  const int mt = w & 1, g = w >> 1;
  const int n = blockIdx.x & 63;            // same-n blocks -> same XCD (64%8==0)
  const int b0 = (blockIdx.x >> 6) * BB;
  const long pn = (long)n * PSTRIDE;
  const int c0 = g * 16 + l15, c1 = c0 + 64;

  const __bf16* __restrict__ wzr = ws + n * ZR_PER_N;
  const __bf16* __restrict__ wh  = ws + H_BASE + n * H_PER_N;
  const __bf16* __restrict__ wg  = ws + G_BASE + n * G_PER_N;

  const float zb0 = p[pn + OFF_ZB + c0], zb1 = p[pn + OFF_ZB + c1];
  const float rb0 = p[pn + OFF_RB + c0], rb1 = p[pn + OFF_RB + c1];
  const float hb0 = p[pn + OFF_HB + c0], hb1 = p[pn + OFF_HB + c1];
  const float gb0 = p[pn + OFF_GHB + c0], gb1 = p[pn + OFF_GHB + c1];

  // phase-A mapping: thread -> (row, 4-wide i block)
  const int arow = tid >> 4;
  const int ai0 = (tid & 15) * 4;
  const int amt = arow >> 4;
  const int akt = ai0 >> 5;
  const int alane = ((ai0 >> 3) & 3) * 16 + (arow & 15);
  const int aj0 = ai0 & 7;
  const float* __restrict__ Xp  = X  + (long)(b0 + arow) * TT * II + ai0;
  const float* __restrict__ XLp = XL + (long)(b0 + arow) * TT * II + ai0;
  const float* __restrict__ MKp = MK + ((long)(n * BATCH + b0 + arow) * TT) * II + ai0;
  const float* __restrict__ DEp = DE + ((long)(n * BATCH + b0 + arow) * TT) * II + ai0;
  float gxd4[4], gxb4[4];
#pragma unroll
  for (int u = 0; u < 4; ++u) {
    gxd4[u] = p[pn + OFF_GXW + (ai0 + u) * 65];  // diagonal of gxw
    gxb4[u] = p[pn + OFF_GXB + ai0 + u];
  }

  float h0[4] = {0.f, 0.f, 0.f, 0.f}, h1[4] = {0.f, 0.f, 0.f, 0.f};

  for (int t = 0; t < TT; ++t) {
    // ---- Phase A: x elementwise; write comb x/m + dls in A-frag layout ----
    {
      const long to = (long)t * II;
      const float4 x4  = *(const float4*)(Xp + to);
      const float4 xl4 = *(const float4*)(XLp + to);
      const float4 m4  = *(const float4*)(MKp + to);
      const float4 d4  = *(const float4*)(DEp + to);
      const float4 xm4 = *(const float4*)(XM + to + ai0);
      bf16x4 xh, xl_, mh, dh_, dl_;
      const bf16x4 zero4 = {(__bf16)0.f, (__bf16)0.f, (__bf16)0.f, (__bf16)0.f};
#pragma unroll
      for (int u = 0; u < 4; ++u) {
        float m = (&m4.x)[u], d = (&d4.x)[u];
        float dx = __expf(-fmaxf(fmaf(d, gxd4[u], gxb4[u]), 0.f));
        float xv = m * (&x4.x)[u] +
                   (1.f - m) * (dx * (&xl4.x)[u] + (1.f - dx) * (&xm4.x)[u]);
        __bf16 vh = (__bf16)xv;
        xh[u] = vh; xl_[u] = (__bf16)(xv - (float)vh);
        mh[u] = (__bf16)m;
        __bf16 dvh = (__bf16)d;
        dh_[u] = dvh; dl_[u] = (__bf16)(d - (float)dvh);
      }
      *(bf16x4*)&combA_hi[amt][akt][alane][aj0] = xh;       // k = i (0..63)
      *(bf16x4*)&combA_lo[amt][akt][alane][aj0] = xl_;
      *(bf16x4*)&combA_hi[amt][6 + akt][alane][aj0] = mh;   // k = 192+i
      *(bf16x4*)&combA_lo[amt][6 + akt][alane][aj0] = zero4;
      *(bf16x4*)&dls_hi[amt][akt][alane][aj0] = dh_;
      *(bf16x4*)&dls_lo[amt][akt][alane][aj0] = dl_;
    }
    __syncthreads();

    // ---- Phase B: delta_h MFMA; h *= exp(-relu(.)); write h into comb ----
    {
      f32x4 ad0 = {0.f, 0.f, 0.f, 0.f}, ad1 = {0.f, 0.f, 0.f, 0.f};
#pragma unroll
      for (int kt = 0; kt < 2; ++kt) {
        bf16x8 ah = *(const bf16x8*)&dls_hi[mt][kt][l][0];
        bf16x8 al = *(const bf16x8*)&dls_lo[mt][kt][l][0];
        const __bf16* kb = wg + kt * 8192 + l * 8;
        bf16x8 bh = *(const bf16x8*)(kb + g * 1024);
        bf16x8 bl = *(const bf16x8*)(kb + g * 1024 + 512);
        ad0 = mfma16(ah, bh, ad0); ad0 = mfma16(al, bh, ad0); ad0 = mfma16(ah, bl, ad0);
        bh = *(const bf16x8*)(kb + (g + 4) * 1024);
        bl = *(const bf16x8*)(kb + (g + 4) * 1024 + 512);
        ad1 = mfma16(ah, bh, ad1); ad1 = mfma16(al, bh, ad1); ad1 = mfma16(ah, bl, ad1);
      }
#pragma unroll
      for (int r = 0; r < 4; ++r) {
        h0[r] *= __expf(-fmaxf(ad0[r] + gb0, 0.f));
        h1[r] *= __expf(-fmaxf(ad1[r] + gb1, 0.f));
        // comb h-region: k = 64 + c
        int lane0 = ((c0 >> 3) & 3) * 16 + lg * 4 + r;
        int lane1 = ((c1 >> 3) & 3) * 16 + lg * 4 + r;
        int kt0 = (64 + c0) >> 5, kt1 = (64 + c1) >> 5;
        __bf16 v0 = (__bf16)h0[r], v1 = (__bf16)h1[r];
        combA_hi[mt][kt0][lane0][c0 & 7] = v0;
        combA_lo[mt][kt0][lane0][c0 & 7] = (__bf16)(h0[r] - (float)v0);
        combA_hi[mt][kt1][lane1][c1 & 7] = v1;
        combA_lo[mt][kt1][lane1][c1 & 7] = (__bf16)(h1[r] - (float)v1);
      }
    }
    __syncthreads();

    // ---- Phase C1: z,r MFMA over comb ----
    float zv0[4], zv1[4], rv0[4], rv1[4];
    {
      f32x4 az0 = {0.f,0.f,0.f,0.f}, az1 = {0.f,0.f,0.f,0.f};
      f32x4 ar0 = {0.f,0.f,0.f,0.f}, ar1 = {0.f,0.f,0.f,0.f};
#pragma unroll
      for (int kt = 0; kt < 8; ++kt) {
        bf16x8 ah = *(const bf16x8*)&combA_hi[mt][kt][l][0];
        bf16x8 al = *(const bf16x8*)&combA_lo[mt][kt][l][0];
        const __bf16* kb = wzr + kt * 16384 + l * 8;
        bf16x8 bh, bl;
        bh = *(const bf16x8*)(kb + g * 1024);        bl = *(const bf16x8*)(kb + g * 1024 + 512);
        az0 = mfma16(ah, bh, az0); az0 = mfma16(al, bh, az0); az0 = mfma16(ah, bl, az0);
        bh = *(const bf16x8*)(kb + (g + 4) * 1024);  bl = *(const bf16x8*)(kb + (g + 4) * 1024 + 512);
        az1 = mfma16(ah, bh, az1); az1 = mfma16(al, bh, az1); az1 = mfma16(ah, bl, az1);
        bh = *(const bf16x8*)(kb + (g + 8) * 1024);  bl = *(const bf16x8*)(kb + (g + 8) * 1024 + 512);
        ar0 = mfma16(ah, bh, ar0); ar0 = mfma16(al, bh, ar0); ar0 = mfma16(ah, bl, ar0);
        bh = *(const bf16x8*)(kb + (g + 12) * 1024); bl = *(const bf16x8*)(kb + (g + 12) * 1024 + 512);
        ar1 = mfma16(ah, bh, ar1); ar1 = mfma16(al, bh, ar1); ar1 = mfma16(ah, bl, ar1);
      }
#pragma unroll
      for (int r = 0; r < 4; ++r) {
        zv0[r] = sigmoidf_(az0[r] + zb0); zv1[r] = sigmoidf_(az1[r] + zb1);
        rv0[r] = sigmoidf_(ar0[r] + rb0); rv1[r] = sigmoidf_(ar1[r] + rb1);
      }
    }
    __syncthreads();

    // ---- Phase C2: overwrite comb h-region with r*h ----
#pragma unroll
    for (int r = 0; r < 4; ++r) {
      float p0 = rv0[r] * h0[r], p1 = rv1[r] * h1[r];
      int lane0 = ((c0 >> 3) & 3) * 16 + lg * 4 + r;
      int lane1 = ((c1 >> 3) & 3) * 16 + lg * 4 + r;
      int kt0 = (64 + c0) >> 5, kt1 = (64 + c1) >> 5;
      __bf16 v0 = (__bf16)p0, v1 = (__bf16)p1;
      combA_hi[mt][kt0][lane0][c0 & 7] = v0;
      combA_lo[mt][kt0][lane0][c0 & 7] = (__bf16)(p0 - (float)v0);
      combA_hi[mt][kt1][lane1][c1 & 7] = v1;
      combA_lo[mt][kt1][lane1][c1 & 7] = (__bf16)(p1 - (float)v1);
    }
    __syncthreads();

    // ---- Phase D1: h_tilde MFMA ----
    {
      f32x4 ahh0 = {0.f,0.f,0.f,0.f}, ahh1 = {0.f,0.f,0.f,0.f};
#pragma unroll
      for (int kt = 0; kt < 8; ++kt) {
        bf16x8 ah = *(const bf16x8*)&combA_hi[mt][kt][l][0];
        bf16x8 al = *(const bf16x8*)&combA_lo[mt][kt][l][0];
        const __bf16* kb = wh + kt * 8192 + l * 8;
        bf16x8 bh = *(const bf16x8*)(kb + g * 1024);
        bf16x8 bl = *(const bf16x8*)(kb + g * 1024 + 512);
        ahh0 = mfma16(ah, bh, ahh0); ahh0 = mfma16(al, bh, ahh0); ahh0 = mfma16(ah, bl, ahh0);
        bh = *(const bf16x8*)(kb + (g + 4) * 1024);
        bl = *(const bf16x8*)(kb + (g + 4) * 1024 + 512);
        ahh1 = mfma16(ah, bh, ahh1); ahh1 = mfma16(al, bh, ahh1); ahh1 = mfma16(ah, bl, ahh1);
      }
      // ---- Phase D2: h = (1-z)h + z*tanh(.) (register-local) ----
#pragma unroll
      for (int r = 0; r < 4; ++r) {
        float ht0 = tanhf(ahh0[r] + hb0);
        float ht1 = tanhf(ahh1[r] + hb1);
        h0[r] = (1.f - zv0[r]) * h0[r] + zv0[r] * ht0;
        h1[r] = (1.f - zv1[r]) * h1[r] + zv1[r] * ht1;
      }
    }
    __syncthreads();
  }

  // ---- fc epilogue ----
#pragma unroll
  for (int r = 0; r < 4; ++r) {
    int row = mt * 16 + lg * 4 + r;
    hstage[row][c0] = h0[r];
    hstage[row][c1] = h1[r];
  }
  __syncthreads();
  if (tid < BB) {
    float acc = p[pn + OFF_FCB];
    for (int j = 0; j < HH; ++j) acc = fmaf(hstage[tid][j], p[pn + OFF_FCW + j], acc);
    out[n * BATCH + b0 + tid] = sigmoidf_(acc);
  }
}

extern "C" void kernel_launch(void* const* d_in, const int* in_sizes, int n_in,
                              void* d_out, int out_size, void* d_ws, size_t ws_size,
                              hipStream_t stream) {
  const float* p  = (const float*)d_in[0];
  const float* X  = (const float*)d_in[1];
  const float* XL = (const float*)d_in[2];
  const float* XM = (const float*)d_in[3];
  const float* MK = (const float*)d_in[4];
  const float* DE = (const float*)d_in[5];
  float* out = (float*)d_out;
  __bf16* ws = (__bf16*)d_ws;
  if (ws_size < (size_t)WS_ELEMS * 2) return;  // ~26 MB scratch

  hipLaunchKernelGGL(repack_kernel, dim3(4096), dim3(256), 0, stream, p, ws);
  hipLaunchKernelGGL(grud_main, dim3(NF * (BATCH / BB)), dim3(NTHR), 0, stream,
                     p, X, XL, XM, MK, DE, ws, out);
}

// Round 4
// 2306.213 us; speedup vs baseline: 2.1508x; 1.1683x over previous
//
#include <hip/hip_runtime.h>

// GRU-D: nf=64, B=128, T=100, I=64, H=128, C=256. MFMA 16x16x32 bf16, 3-term hi/lo.
// R4 = R3 with ext-vector types for nontemporal loads (compile fix).
#define NF 64
#define BATCH 128
#define TT 100
#define II 64
#define HH 128
#define CC 256
#define BB 16
#define NTHR 512
#define PSTRIDE 111297

#define OFF_ZW 0
#define OFF_ZB 32768
#define OFF_RW 32896
#define OFF_RB 65664
#define OFF_HW 65792
#define OFF_HB 98560
#define OFF_GXW 98688
#define OFF_GXB 102784
#define OFF_GHW 102848
#define OFF_GHB 111040
#define OFF_FCW 111168
#define OFF_FCB 111296

// ws layout (bf16 elems), per-lane MFMA B-fragment order:
//  frag addr = region + n*PER_N + (kt*NT + nt)*1024 + s*512 + l*8 + j   (s: 0=hi,1=lo)
#define ZR_PER_N 131072
#define H_BASE   (64 * ZR_PER_N)
#define H_PER_N  65536
#define G_BASE   (H_BASE + 64 * H_PER_N)
#define G_PER_N  16384
#define WS_ELEMS (G_BASE + 64 * G_PER_N)   // 13631488 bf16 = 26 MB

typedef __bf16 bf16x8 __attribute__((ext_vector_type(8)));
typedef __bf16 bf16x2 __attribute__((ext_vector_type(2)));
typedef float f32x4 __attribute__((ext_vector_type(4)));
typedef float f32x2 __attribute__((ext_vector_type(2)));

__device__ __forceinline__ f32x4 mfma16(bf16x8 a, bf16x8 b, f32x4 c) {
  return __builtin_amdgcn_mfma_f32_16x16x32_bf16(a, b, c, 0, 0, 0);
}
__device__ __forceinline__ float sigmoidf_(float x) { return 1.f / (1.f + __expf(-x)); }

// ---- repack: params -> B-fragment-ordered bf16 hi/lo in ws ----
__global__ void repack_kernel(const float* __restrict__ p, __bf16* __restrict__ ws) {
  const int total = 4194304 + 2097152 + 524288;
  for (int e = blockIdx.x * 256 + threadIdx.x; e < total; e += gridDim.x * 256) {
    float wv; int dst;
    if (e < 4194304) {  // ZR: [z cols 0..127 | r cols 0..127], K=256
      int j = e & 7, l = (e >> 3) & 63, nt = (e >> 9) & 15, kt = (e >> 13) & 7, n = e >> 16;
      int c = kt * 32 + (l >> 4) * 8 + j, l15 = l & 15;
      long pn = (long)n * PSTRIDE;
      wv = (nt < 8) ? p[pn + OFF_ZW + (nt * 16 + l15) * CC + c]
                    : p[pn + OFF_RW + ((nt - 8) * 16 + l15) * CC + c];
      dst = n * ZR_PER_N + (kt * 16 + nt) * 1024 + l * 8 + j;
    } else if (e < 4194304 + 2097152) {  // H: h_tilde weights, K=256
      int e2 = e - 4194304;
      int j = e2 & 7, l = (e2 >> 3) & 63, nt = (e2 >> 9) & 7, kt = (e2 >> 12) & 7, n = e2 >> 15;
      int c = kt * 32 + (l >> 4) * 8 + j, l15 = l & 15;
      wv = p[(long)n * PSTRIDE + OFF_HW + (nt * 16 + l15) * CC + c];
      dst = H_BASE + n * H_PER_N + (kt * 8 + nt) * 1024 + l * 8 + j;
    } else {  // G: ghw [128][64], K=64
      int e2 = e - (4194304 + 2097152);
      int j = e2 & 7, l = (e2 >> 3) & 63, nt = (e2 >> 9) & 7, kt = (e2 >> 12) & 1, n = e2 >> 13;
      int c = kt * 32 + (l >> 4) * 8 + j, l15 = l & 15;
      wv = p[(long)n * PSTRIDE + OFF_GHW + (nt * 16 + l15) * II + c];
      dst = G_BASE + n * G_PER_N + (kt * 8 + nt) * 1024 + l * 8 + j;
    }
    __bf16 hi = (__bf16)wv;
    __bf16 lo = (__bf16)(wv - (float)hi);
    ws[dst] = hi;
    ws[dst + 512] = lo;
  }
}

// One block per (n, 16-batch chunk), persistent over T. 8 waves.
// Wave w owns cols cw = w*16 + (l&15) for delta_h, z, r, h_tilde, h — all
// register-local per lane (rows lg*4+r). 512 blocks -> 2 blocks/CU.
__global__ __launch_bounds__(NTHR, 4) void grud_main(
    const float* __restrict__ p, const float* __restrict__ X,
    const float* __restrict__ XL, const float* __restrict__ XM,
    const float* __restrict__ MK, const float* __restrict__ DE,
    const __bf16* __restrict__ ws, float* __restrict__ out) {
  // A-frag layout: [kt][lane][8], lane = ((k'>>3)&3)*16 + row, j = k'&7, k' = k&31
  __shared__ __align__(16) __bf16 combA_hi[8][64][8];  // k: x[0,64) h[64,192) m[192,256)
  __shared__ __align__(16) __bf16 combA_lo[8][64][8];
  __shared__ __align__(16) __bf16 rhA_hi[4][64][8];    // r*h region (k in [64,192))
  __shared__ __align__(16) __bf16 rhA_lo[4][64][8];
  __shared__ __align__(16) __bf16 dls_hi[2][64][8];
  __shared__ __align__(16) __bf16 dls_lo[2][64][8];
  __shared__ float hstage[BB][132];

  const int tid = threadIdx.x;
  const int w = tid >> 6, l = tid & 63;
  const int l15 = l & 15, lg = l >> 4;
  const int n = blockIdx.x & 63;            // same-n blocks -> same XCD
  const int b0 = (blockIdx.x >> 6) * BB;
  const long pn = (long)n * PSTRIDE;
  const int cw = w * 16 + l15;              // this wave/lane's output column

  const __bf16* __restrict__ wzr = ws + n * ZR_PER_N;
  const __bf16* __restrict__ wh  = ws + H_BASE + n * H_PER_N;
  const __bf16* __restrict__ wg  = ws + G_BASE + n * G_PER_N;

  const float zb = p[pn + OFF_ZB + cw];
  const float rb = p[pn + OFF_RB + cw];
  const float hb = p[pn + OFF_HB + cw];
  const float gb = p[pn + OFF_GHB + cw];

  // LDS coords for this lane's h column (global k = 64 + cw)
  const int hkt = (64 + cw) >> 5;                       // 2..5
  const int hlane_base = (((64 + cw) >> 3) & 3) * 16;
  const int hj = cw & 7;

  // phase-A mapping: thread -> (row, 2-wide i block)
  const int arow = tid >> 5;         // 0..15
  const int ai0 = (tid & 31) * 2;    // 0..62 (even)
  const int akt = ai0 >> 5;
  const int alane = ((ai0 >> 3) & 3) * 16 + arow;
  const int aj = ai0 & 7;
  const float* __restrict__ Xp  = X  + (long)(b0 + arow) * TT * II + ai0;
  const float* __restrict__ XLp = XL + (long)(b0 + arow) * TT * II + ai0;
  const float* __restrict__ MKp = MK + ((long)(n * BATCH + b0 + arow) * TT) * II + ai0;
  const float* __restrict__ DEp = DE + ((long)(n * BATCH + b0 + arow) * TT) * II + ai0;
  const float gxd0 = p[pn + OFF_GXW + ai0 * 65];
  const float gxd1 = p[pn + OFF_GXW + (ai0 + 1) * 65];
  const float gxb0 = p[pn + OFF_GXB + ai0];
  const float gxb1 = p[pn + OFF_GXB + ai0 + 1];

  float h[4] = {0.f, 0.f, 0.f, 0.f};

  // prefetch t=0 inputs
  f32x2 fx  = *(const f32x2*)Xp;
  f32x2 fxl = *(const f32x2*)XLp;
  f32x2 fxm = *(const f32x2*)(XM + ai0);
  f32x2 fm  = __builtin_nontemporal_load((const f32x2*)MKp);
  f32x2 fd  = __builtin_nontemporal_load((const f32x2*)DEp);

  for (int t = 0; t < TT; ++t) {
    // ---- Phase A: elementwise x from prefetched regs; write LDS A-frags ----
    {
      float m0 = fm[0], m1 = fm[1], d0 = fd[0], d1 = fd[1];
      float dx0 = __expf(-fmaxf(fmaf(d0, gxd0, gxb0), 0.f));
      float dx1 = __expf(-fmaxf(fmaf(d1, gxd1, gxb1), 0.f));
      float xv0 = m0 * fx[0] + (1.f - m0) * (dx0 * fxl[0] + (1.f - dx0) * fxm[0]);
      float xv1 = m1 * fx[1] + (1.f - m1) * (dx1 * fxl[1] + (1.f - dx1) * fxm[1]);
      __bf16 x0h = (__bf16)xv0, x1h = (__bf16)xv1;
      __bf16 d0h = (__bf16)d0, d1h = (__bf16)d1;
      *(bf16x2*)&combA_hi[akt][alane][aj] = bf16x2{x0h, x1h};
      *(bf16x2*)&combA_lo[akt][alane][aj] =
          bf16x2{(__bf16)(xv0 - (float)x0h), (__bf16)(xv1 - (float)x1h)};
      *(bf16x2*)&combA_hi[6 + akt][alane][aj] = bf16x2{(__bf16)m0, (__bf16)m1};
      *(bf16x2*)&combA_lo[6 + akt][alane][aj] = bf16x2{(__bf16)0.f, (__bf16)0.f};
      *(bf16x2*)&dls_hi[akt][alane][aj] = bf16x2{d0h, d1h};
      *(bf16x2*)&dls_lo[akt][alane][aj] =
          bf16x2{(__bf16)(d0 - (float)d0h), (__bf16)(d1 - (float)d1h)};
    }
    __syncthreads();

    // ---- Phase B: prefetch t+1 inputs; delta_h MFMA; h *= exp(-relu) ----
    {
      const long to = (long)(t + 1 < TT ? t + 1 : t) * II;
      fx  = *(const f32x2*)(Xp + to);
      fxl = *(const f32x2*)(XLp + to);
      fxm = *(const f32x2*)(XM + to + ai0);
      fm  = __builtin_nontemporal_load((const f32x2*)(MKp + to));
      fd  = __builtin_nontemporal_load((const f32x2*)(DEp + to));

      f32x4 ad = {0.f, 0.f, 0.f, 0.f};
#pragma unroll
      for (int kt = 0; kt < 2; ++kt) {
        bf16x8 ah = *(const bf16x8*)&dls_hi[kt][l][0];
        bf16x8 al = *(const bf16x8*)&dls_lo[kt][l][0];
        const __bf16* kb = wg + (kt * 8 + w) * 1024 + l * 8;
        bf16x8 bh = *(const bf16x8*)kb;
        bf16x8 bl = *(const bf16x8*)(kb + 512);
        ad = mfma16(ah, bh, ad); ad = mfma16(al, bh, ad); ad = mfma16(ah, bl, ad);
      }
#pragma unroll
      for (int r = 0; r < 4; ++r) {
        h[r] *= __expf(-fmaxf(ad[r] + gb, 0.f));
        int lane = hlane_base + lg * 4 + r;
        __bf16 v = (__bf16)h[r];
        combA_hi[hkt][lane][hj] = v;
        combA_lo[hkt][lane][hj] = (__bf16)(h[r] - (float)v);
      }
    }
    __syncthreads();

    // ---- Phase C: z,r MFMA; write r*h to rhA ----
    float zv[4];
    {
      f32x4 az = {0.f, 0.f, 0.f, 0.f}, ar = {0.f, 0.f, 0.f, 0.f};
#pragma unroll
      for (int kt = 0; kt < 8; ++kt) {
        bf16x8 ah = *(const bf16x8*)&combA_hi[kt][l][0];
        bf16x8 al = *(const bf16x8*)&combA_lo[kt][l][0];
        const __bf16* kz = wzr + (kt * 16 + w) * 1024 + l * 8;
        const __bf16* kr = wzr + (kt * 16 + 8 + w) * 1024 + l * 8;
        bf16x8 bh = *(const bf16x8*)kz;
        bf16x8 bl = *(const bf16x8*)(kz + 512);
        az = mfma16(ah, bh, az); az = mfma16(al, bh, az); az = mfma16(ah, bl, az);
        bh = *(const bf16x8*)kr;
        bl = *(const bf16x8*)(kr + 512);
        ar = mfma16(ah, bh, ar); ar = mfma16(al, bh, ar); ar = mfma16(ah, bl, ar);
      }
#pragma unroll
      for (int r = 0; r < 4; ++r) {
        zv[r] = sigmoidf_(az[r] + zb);
        float rv = sigmoidf_(ar[r] + rb);
        float rh = rv * h[r];
        int lane = hlane_base + lg * 4 + r;
        __bf16 v = (__bf16)rh;
        rhA_hi[hkt - 2][lane][hj] = v;
        rhA_lo[hkt - 2][lane][hj] = (__bf16)(rh - (float)v);
      }
    }
    __syncthreads();

    // ---- Phase D: h_tilde MFMA (x,m from combA; r*h from rhA); h update ----
    {
      f32x4 ahh = {0.f, 0.f, 0.f, 0.f};
#pragma unroll
      for (int kt = 0; kt < 8; ++kt) {
        bf16x8 ah, al;
        if (kt < 2)      { ah = *(const bf16x8*)&combA_hi[kt][l][0];
                           al = *(const bf16x8*)&combA_lo[kt][l][0]; }
        else if (kt < 6) { ah = *(const bf16x8*)&rhA_hi[kt - 2][l][0];
                           al = *(const bf16x8*)&rhA_lo[kt - 2][l][0]; }
        else             { ah = *(const bf16x8*)&combA_hi[kt][l][0];
                           al = *(const bf16x8*)&combA_lo[kt][l][0]; }
        const __bf16* kb = wh + (kt * 8 + w) * 1024 + l * 8;
        bf16x8 bh = *(const bf16x8*)kb;
        bf16x8 bl = *(const bf16x8*)(kb + 512);
        ahh = mfma16(ah, bh, ahh); ahh = mfma16(al, bh, ahh); ahh = mfma16(ah, bl, ahh);
      }
#pragma unroll
      for (int r = 0; r < 4; ++r) {
        float ht = tanhf(ahh[r] + hb);
        h[r] = (1.f - zv[r]) * h[r] + zv[r] * ht;
      }
    }
    __syncthreads();
  }

  // ---- fc epilogue ----
#pragma unroll
  for (int r = 0; r < 4; ++r) hstage[lg * 4 + r][cw] = h[r];
  __syncthreads();
  if (tid < BB) {
    float acc = p[pn + OFF_FCB];
    for (int j = 0; j < HH; ++j) acc = fmaf(hstage[tid][j], p[pn + OFF_FCW + j], acc);
    out[n * BATCH + b0 + tid] = sigmoidf_(acc);
  }
}

extern "C" void kernel_launch(void* const* d_in, const int* in_sizes, int n_in,
                              void* d_out, int out_size, void* d_ws, size_t ws_size,
                              hipStream_t stream) {
  const float* p  = (const float*)d_in[0];
  const float* X  = (const float*)d_in[1];
  const float* XL = (const float*)d_in[2];
  const float* XM = (const float*)d_in[3];
  const float* MK = (const float*)d_in[4];
  const float* DE = (const float*)d_in[5];
  float* out = (float*)d_out;
  __bf16* ws = (__bf16*)d_ws;
  if (ws_size < (size_t)WS_ELEMS * 2) return;

  hipLaunchKernelGGL(repack_kernel, dim3(4096), dim3(256), 0, stream, p, ws);
  hipLaunchKernelGGL(grud_main, dim3(NF * (BATCH / BB)), dim3(NTHR), 0, stream,
                     p, X, XL, XM, MK, DE, ws, out);
}

// Round 5
// 952.958 us; speedup vs baseline: 5.2052x; 2.4201x over previous
//
#include <hip/hip_runtime.h>

// GRU-D: nf=64, B=128, T=100, I=64, H=128, C=256.
// R5: 2-term MFMA (ah*bh + al*bh) — weights bf16-hi only -> L2-resident (1.7 MB/XCD).
#define NF 64
#define BATCH 128
#define TT 100
#define II 64
#define HH 128
#define CC 256
#define BB 16
#define NTHR 512
#define PSTRIDE 111297

#define OFF_ZW 0
#define OFF_ZB 32768
#define OFF_RW 32896
#define OFF_RB 65664
#define OFF_HW 65792
#define OFF_HB 98560
#define OFF_GXW 98688
#define OFF_GXB 102784
#define OFF_GHW 102848
#define OFF_GHB 111040
#define OFF_FCW 111168
#define OFF_FCB 111296

// ws layout (bf16 elems), per-lane MFMA B-fragment order (hi only):
//  frag addr = region + n*PER_N + (kt*NT + nt)*512 + l*8 + j
#define ZR_PER_N 65536
#define H_BASE   (64 * ZR_PER_N)            // 4194304
#define H_PER_N  32768
#define G_BASE   (H_BASE + 64 * H_PER_N)    // 6291456
#define G_PER_N  8192
#define WS_ELEMS (G_BASE + 64 * G_PER_N)    // 6815744 bf16 = 13 MB

typedef __bf16 bf16x8 __attribute__((ext_vector_type(8)));
typedef __bf16 bf16x2 __attribute__((ext_vector_type(2)));
typedef float f32x4 __attribute__((ext_vector_type(4)));
typedef float f32x2 __attribute__((ext_vector_type(2)));

__device__ __forceinline__ f32x4 mfma16(bf16x8 a, bf16x8 b, f32x4 c) {
  return __builtin_amdgcn_mfma_f32_16x16x32_bf16(a, b, c, 0, 0, 0);
}
__device__ __forceinline__ float sigmoidf_(float x) { return 1.f / (1.f + __expf(-x)); }

// ---- repack: params -> B-fragment-ordered bf16 (hi only) in ws ----
__global__ void repack_kernel(const float* __restrict__ p, __bf16* __restrict__ ws) {
  const int total = 4194304 + 2097152 + 524288;
  for (int e = blockIdx.x * 256 + threadIdx.x; e < total; e += gridDim.x * 256) {
    float wv; int dst;
    if (e < 4194304) {  // ZR: [z cols 0..127 | r cols 0..127], K=256
      int j = e & 7, l = (e >> 3) & 63, nt = (e >> 9) & 15, kt = (e >> 13) & 7, n = e >> 16;
      int c = kt * 32 + (l >> 4) * 8 + j, l15 = l & 15;
      long pn = (long)n * PSTRIDE;
      wv = (nt < 8) ? p[pn + OFF_ZW + (nt * 16 + l15) * CC + c]
                    : p[pn + OFF_RW + ((nt - 8) * 16 + l15) * CC + c];
      dst = n * ZR_PER_N + (kt * 16 + nt) * 512 + l * 8 + j;
    } else if (e < 4194304 + 2097152) {  // H: h_tilde weights, K=256
      int e2 = e - 4194304;
      int j = e2 & 7, l = (e2 >> 3) & 63, nt = (e2 >> 9) & 7, kt = (e2 >> 12) & 7, n = e2 >> 15;
      int c = kt * 32 + (l >> 4) * 8 + j, l15 = l & 15;
      wv = p[(long)n * PSTRIDE + OFF_HW + (nt * 16 + l15) * CC + c];
      dst = H_BASE + n * H_PER_N + (kt * 8 + nt) * 512 + l * 8 + j;
    } else {  // G: ghw [128][64], K=64
      int e2 = e - (4194304 + 2097152);
      int j = e2 & 7, l = (e2 >> 3) & 63, nt = (e2 >> 9) & 7, kt = (e2 >> 12) & 1, n = e2 >> 13;
      int c = kt * 32 + (l >> 4) * 8 + j, l15 = l & 15;
      wv = p[(long)n * PSTRIDE + OFF_GHW + (nt * 16 + l15) * II + c];
      dst = G_BASE + n * G_PER_N + (kt * 8 + nt) * 512 + l * 8 + j;
    }
    ws[dst] = (__bf16)wv;
  }
}

// One block per (n, 16-batch chunk), persistent over T. 8 waves.
// Wave w owns cols cw = w*16 + (l&15); h/z/r/h_tilde register-local per lane.
__global__ __launch_bounds__(NTHR, 4) void grud_main(
    const float* __restrict__ p, const float* __restrict__ X,
    const float* __restrict__ XL, const float* __restrict__ XM,
    const float* __restrict__ MK, const float* __restrict__ DE,
    const __bf16* __restrict__ ws, float* __restrict__ out) {
  // A-frag layout: [kt][lane][8], lane = ((k'>>3)&3)*16 + row, j = k'&7, k' = k&31
  __shared__ __align__(16) __bf16 combA_hi[8][64][8];  // k: x[0,64) h[64,192) m[192,256)
  __shared__ __align__(16) __bf16 combA_lo[8][64][8];
  __shared__ __align__(16) __bf16 rhA_hi[4][64][8];    // r*h region (k in [64,192))
  __shared__ __align__(16) __bf16 rhA_lo[4][64][8];
  __shared__ __align__(16) __bf16 dls_hi[2][64][8];
  __shared__ __align__(16) __bf16 dls_lo[2][64][8];
  __shared__ float hstage[BB][132];

  const int tid = threadIdx.x;
  const int w = tid >> 6, l = tid & 63;
  const int l15 = l & 15, lg = l >> 4;
  const int n = blockIdx.x & 63;            // same-n blocks -> same XCD
  const int b0 = (blockIdx.x >> 6) * BB;
  const long pn = (long)n * PSTRIDE;
  const int cw = w * 16 + l15;              // this wave/lane's output column

  const __bf16* __restrict__ wzr = ws + n * ZR_PER_N;
  const __bf16* __restrict__ wh  = ws + H_BASE + n * H_PER_N;
  const __bf16* __restrict__ wg  = ws + G_BASE + n * G_PER_N;

  const float zb = p[pn + OFF_ZB + cw];
  const float rb = p[pn + OFF_RB + cw];
  const float hb = p[pn + OFF_HB + cw];
  const float gb = p[pn + OFF_GHB + cw];

  // LDS coords for this lane's h column (global k = 64 + cw)
  const int hkt = (64 + cw) >> 5;                       // 2..5
  const int hlane_base = (((64 + cw) >> 3) & 3) * 16;
  const int hj = cw & 7;

  // phase-A mapping: thread -> (row, 2-wide i block)
  const int arow = tid >> 5;         // 0..15
  const int ai0 = (tid & 31) * 2;    // 0..62 (even)
  const int akt = ai0 >> 5;
  const int alane = ((ai0 >> 3) & 3) * 16 + arow;
  const int aj = ai0 & 7;
  const float* __restrict__ Xp  = X  + (long)(b0 + arow) * TT * II + ai0;
  const float* __restrict__ XLp = XL + (long)(b0 + arow) * TT * II + ai0;
  const float* __restrict__ MKp = MK + ((long)(n * BATCH + b0 + arow) * TT) * II + ai0;
  const float* __restrict__ DEp = DE + ((long)(n * BATCH + b0 + arow) * TT) * II + ai0;
  const float gxd0 = p[pn + OFF_GXW + ai0 * 65];
  const float gxd1 = p[pn + OFF_GXW + (ai0 + 1) * 65];
  const float gxb0 = p[pn + OFF_GXB + ai0];
  const float gxb1 = p[pn + OFF_GXB + ai0 + 1];

  float h[4] = {0.f, 0.f, 0.f, 0.f};

  // constant-zero lo of the mask region: write once
  *(bf16x2*)&combA_lo[6 + akt][alane][aj] = bf16x2{(__bf16)0.f, (__bf16)0.f};

  // prefetch t=0 inputs
  f32x2 fx  = *(const f32x2*)Xp;
  f32x2 fxl = *(const f32x2*)XLp;
  f32x2 fxm = *(const f32x2*)(XM + ai0);
  f32x2 fm  = __builtin_nontemporal_load((const f32x2*)MKp);
  f32x2 fd  = __builtin_nontemporal_load((const f32x2*)DEp);

  for (int t = 0; t < TT; ++t) {
    // ---- Phase A: elementwise x from prefetched regs; write LDS A-frags ----
    {
      float m0 = fm[0], m1 = fm[1], d0 = fd[0], d1 = fd[1];
      float dx0 = __expf(-fmaxf(fmaf(d0, gxd0, gxb0), 0.f));
      float dx1 = __expf(-fmaxf(fmaf(d1, gxd1, gxb1), 0.f));
      float xv0 = m0 * fx[0] + (1.f - m0) * (dx0 * fxl[0] + (1.f - dx0) * fxm[0]);
      float xv1 = m1 * fx[1] + (1.f - m1) * (dx1 * fxl[1] + (1.f - dx1) * fxm[1]);
      __bf16 x0h = (__bf16)xv0, x1h = (__bf16)xv1;
      __bf16 d0h = (__bf16)d0, d1h = (__bf16)d1;
      *(bf16x2*)&combA_hi[akt][alane][aj] = bf16x2{x0h, x1h};
      *(bf16x2*)&combA_lo[akt][alane][aj] =
          bf16x2{(__bf16)(xv0 - (float)x0h), (__bf16)(xv1 - (float)x1h)};
      *(bf16x2*)&combA_hi[6 + akt][alane][aj] = bf16x2{(__bf16)m0, (__bf16)m1};
      *(bf16x2*)&dls_hi[akt][alane][aj] = bf16x2{d0h, d1h};
      *(bf16x2*)&dls_lo[akt][alane][aj] =
          bf16x2{(__bf16)(d0 - (float)d0h), (__bf16)(d1 - (float)d1h)};
    }
    __syncthreads();

    // ---- Phase B: prefetch t+1 inputs; delta_h MFMA; h *= exp(-relu) ----
    {
      const long to = (long)(t + 1 < TT ? t + 1 : t) * II;
      fx  = *(const f32x2*)(Xp + to);
      fxl = *(const f32x2*)(XLp + to);
      fxm = *(const f32x2*)(XM + to + ai0);
      fm  = __builtin_nontemporal_load((const f32x2*)(MKp + to));
      fd  = __builtin_nontemporal_load((const f32x2*)(DEp + to));

      f32x4 ad = {0.f, 0.f, 0.f, 0.f};
#pragma unroll
      for (int kt = 0; kt < 2; ++kt) {
        bf16x8 ah = *(const bf16x8*)&dls_hi[kt][l][0];
        bf16x8 al = *(const bf16x8*)&dls_lo[kt][l][0];
        bf16x8 bh = *(const bf16x8*)(wg + (kt * 8 + w) * 512 + l * 8);
        ad = mfma16(ah, bh, ad); ad = mfma16(al, bh, ad);
      }
#pragma unroll
      for (int r = 0; r < 4; ++r) {
        h[r] *= __expf(-fmaxf(ad[r] + gb, 0.f));
        int lane = hlane_base + lg * 4 + r;
        __bf16 v = (__bf16)h[r];
        combA_hi[hkt][lane][hj] = v;
        combA_lo[hkt][lane][hj] = (__bf16)(h[r] - (float)v);
      }
    }
    __syncthreads();

    // ---- Phase C: z,r MFMA; write r*h to rhA ----
    float zv[4];
    {
      f32x4 az = {0.f, 0.f, 0.f, 0.f}, ar = {0.f, 0.f, 0.f, 0.f};
#pragma unroll
      for (int kt = 0; kt < 8; ++kt) {
        bf16x8 ah = *(const bf16x8*)&combA_hi[kt][l][0];
        bf16x8 al = *(const bf16x8*)&combA_lo[kt][l][0];
        bf16x8 bz = *(const bf16x8*)(wzr + (kt * 16 + w) * 512 + l * 8);
        bf16x8 br = *(const bf16x8*)(wzr + (kt * 16 + 8 + w) * 512 + l * 8);
        az = mfma16(ah, bz, az); az = mfma16(al, bz, az);
        ar = mfma16(ah, br, ar); ar = mfma16(al, br, ar);
      }
#pragma unroll
      for (int r = 0; r < 4; ++r) {
        zv[r] = sigmoidf_(az[r] + zb);
        float rv = sigmoidf_(ar[r] + rb);
        float rh = rv * h[r];
        int lane = hlane_base + lg * 4 + r;
        __bf16 v = (__bf16)rh;
        rhA_hi[hkt - 2][lane][hj] = v;
        rhA_lo[hkt - 2][lane][hj] = (__bf16)(rh - (float)v);
      }
    }
    __syncthreads();

    // ---- Phase D: h_tilde MFMA (x,m from combA; r*h from rhA); h update ----
    {
      f32x4 ahh = {0.f, 0.f, 0.f, 0.f};
#pragma unroll
      for (int kt = 0; kt < 8; ++kt) {
        bf16x8 ah, al;
        if (kt < 2)      { ah = *(const bf16x8*)&combA_hi[kt][l][0];
                           al = *(const bf16x8*)&combA_lo[kt][l][0]; }
        else if (kt < 6) { ah = *(const bf16x8*)&rhA_hi[kt - 2][l][0];
                           al = *(const bf16x8*)&rhA_lo[kt - 2][l][0]; }
        else             { ah = *(const bf16x8*)&combA_hi[kt][l][0];
                           al = *(const bf16x8*)&combA_lo[kt][l][0]; }
        bf16x8 bh = *(const bf16x8*)(wh + (kt * 8 + w) * 512 + l * 8);
        ahh = mfma16(ah, bh, ahh); ahh = mfma16(al, bh, ahh);
      }
#pragma unroll
      for (int r = 0; r < 4; ++r) {
        float ht = tanhf(ahh[r] + hb);
        h[r] = (1.f - zv[r]) * h[r] + zv[r] * ht;
      }
    }
    __syncthreads();
  }

  // ---- fc epilogue ----
#pragma unroll
  for (int r = 0; r < 4; ++r) hstage[lg * 4 + r][cw] = h[r];
  __syncthreads();
  if (tid < BB) {
    float acc = p[pn + OFF_FCB];
    for (int j = 0; j < HH; ++j) acc = fmaf(hstage[tid][j], p[pn + OFF_FCW + j], acc);
    out[n * BATCH + b0 + tid] = sigmoidf_(acc);
  }
}

extern "C" void kernel_launch(void* const* d_in, const int* in_sizes, int n_in,
                              void* d_out, int out_size, void* d_ws, size_t ws_size,
                              hipStream_t stream) {
  const float* p  = (const float*)d_in[0];
  const float* X  = (const float*)d_in[1];
  const float* XL = (const float*)d_in[2];
  const float* XM = (const float*)d_in[3];
  const float* MK = (const float*)d_in[4];
  const float* DE = (const float*)d_in[5];
  float* out = (float*)d_out;
  __bf16* ws = (__bf16*)d_ws;
  if (ws_size < (size_t)WS_ELEMS * 2) return;

  hipLaunchKernelGGL(repack_kernel, dim3(4096), dim3(256), 0, stream, p, ws);
  hipLaunchKernelGGL(grud_main, dim3(NF * (BATCH / BB)), dim3(NTHR), 0, stream,
                     p, X, XL, XM, MK, DE, ws, out);
}

// Round 6
// 474.610 us; speedup vs baseline: 10.4513x; 2.0079x over previous
//
#include <hip/hip_runtime.h>

// GRU-D: nf=64, B=128, T=100, I=64, H=128, C=256.
// R6: weights held in REGISTERS (104 VGPR/lane) across all 100 steps.
//     BB=32, grid=256 (1 block/CU), 2-term MFMA (act hi/lo x weight hi).
#define NF 64
#define BATCH 128
#define TT 100
#define II 64
#define HH 128
#define CC 256
#define BB 32
#define NTHR 512
#define PSTRIDE 111297

#define OFF_ZW 0
#define OFF_ZB 32768
#define OFF_RW 32896
#define OFF_RB 65664
#define OFF_HW 65792
#define OFF_HB 98560
#define OFF_GXW 98688
#define OFF_GXB 102784
#define OFF_GHW 102848
#define OFF_GHB 111040
#define OFF_FCW 111168
#define OFF_FCB 111296

// ws layout (bf16 elems), per-lane MFMA B-fragment order (hi only):
//  frag addr = region + n*PER_N + (kt*NT + nt)*512 + l*8 + j
#define ZR_PER_N 65536
#define H_BASE   (64 * ZR_PER_N)
#define H_PER_N  32768
#define G_BASE   (H_BASE + 64 * H_PER_N)
#define G_PER_N  8192
#define WS_ELEMS (G_BASE + 64 * G_PER_N)   // 6815744 bf16 = 13 MB

typedef __bf16 bf16x8 __attribute__((ext_vector_type(8)));
typedef __bf16 bf16x4 __attribute__((ext_vector_type(4)));
typedef float f32x4 __attribute__((ext_vector_type(4)));

__device__ __forceinline__ f32x4 mfma16(bf16x8 a, bf16x8 b, f32x4 c) {
  return __builtin_amdgcn_mfma_f32_16x16x32_bf16(a, b, c, 0, 0, 0);
}
__device__ __forceinline__ float sigmoidf_(float x) { return 1.f / (1.f + __expf(-x)); }

// ---- repack: params -> B-fragment-ordered bf16 (hi only) in ws ----
__global__ void repack_kernel(const float* __restrict__ p, __bf16* __restrict__ ws) {
  const int total = 4194304 + 2097152 + 524288;
  for (int e = blockIdx.x * 256 + threadIdx.x; e < total; e += gridDim.x * 256) {
    float wv; int dst;
    if (e < 4194304) {  // ZR: [z cols 0..127 | r cols 0..127], K=256
      int j = e & 7, l = (e >> 3) & 63, nt = (e >> 9) & 15, kt = (e >> 13) & 7, n = e >> 16;
      int c = kt * 32 + (l >> 4) * 8 + j, l15 = l & 15;
      long pn = (long)n * PSTRIDE;
      wv = (nt < 8) ? p[pn + OFF_ZW + (nt * 16 + l15) * CC + c]
                    : p[pn + OFF_RW + ((nt - 8) * 16 + l15) * CC + c];
      dst = n * ZR_PER_N + (kt * 16 + nt) * 512 + l * 8 + j;
    } else if (e < 4194304 + 2097152) {  // H: h_tilde weights, K=256
      int e2 = e - 4194304;
      int j = e2 & 7, l = (e2 >> 3) & 63, nt = (e2 >> 9) & 7, kt = (e2 >> 12) & 7, n = e2 >> 15;
      int c = kt * 32 + (l >> 4) * 8 + j, l15 = l & 15;
      wv = p[(long)n * PSTRIDE + OFF_HW + (nt * 16 + l15) * CC + c];
      dst = H_BASE + n * H_PER_N + (kt * 8 + nt) * 512 + l * 8 + j;
    } else {  // G: ghw [128][64], K=64
      int e2 = e - (4194304 + 2097152);
      int j = e2 & 7, l = (e2 >> 3) & 63, nt = (e2 >> 9) & 7, kt = (e2 >> 12) & 1, n = e2 >> 13;
      int c = kt * 32 + (l >> 4) * 8 + j, l15 = l & 15;
      wv = p[(long)n * PSTRIDE + OFF_GHW + (nt * 16 + l15) * II + c];
      dst = G_BASE + n * G_PER_N + (kt * 8 + nt) * 512 + l * 8 + j;
    }
    ws[dst] = (__bf16)wv;
  }
}

// One block per (n, 32-batch chunk), persistent over T. 8 waves, 1 block/CU.
// Wave w owns cols cw = w*16 + (l&15) and computes BOTH 16-row tiles (mt=0,1).
// All weight B-fragments live in registers (loaded once).
__global__ __launch_bounds__(NTHR, 2) void grud_main(
    const float* __restrict__ p, const float* __restrict__ X,
    const float* __restrict__ XL, const float* __restrict__ XM,
    const float* __restrict__ MK, const float* __restrict__ DE,
    const __bf16* __restrict__ ws, float* __restrict__ out) {
  // A-frag layout: [mt][kt][lane][8], lane = ((k'>>3)&3)*16 + row, j = k'&7
  __shared__ __align__(16) __bf16 combA_hi[2][8][64][8];  // k: x[0,64) h[64,192) m[192,256)
  __shared__ __align__(16) __bf16 combA_lo[2][8][64][8];  // kt 6,7 unused (m lo == 0)
  __shared__ __align__(16) __bf16 rhA_hi[2][4][64][8];
  __shared__ __align__(16) __bf16 rhA_lo[2][4][64][8];
  __shared__ __align__(16) __bf16 dls_hi[2][2][64][8];
  __shared__ __align__(16) __bf16 dls_lo[2][2][64][8];
  __shared__ float hstage[BB][132];

  const int tid = threadIdx.x;
  const int w = tid >> 6, l = tid & 63;
  const int l15 = l & 15, lg = l >> 4;
  const int n = blockIdx.x & 63;            // same-n blocks -> same XCD
  const int b0 = (blockIdx.x >> 6) * BB;
  const long pn = (long)n * PSTRIDE;
  const int cw = w * 16 + l15;

  // ---- load this wave's weight fragments into registers (once) ----
  bf16x8 wgR[2], wzR[8], wrR[8], whR[8];
  {
    const __bf16* wzr = ws + n * ZR_PER_N;
    const __bf16* wh_ = ws + H_BASE + n * H_PER_N;
    const __bf16* wg_ = ws + G_BASE + n * G_PER_N;
#pragma unroll
    for (int kt = 0; kt < 2; ++kt)
      wgR[kt] = *(const bf16x8*)(wg_ + (kt * 8 + w) * 512 + l * 8);
#pragma unroll
    for (int kt = 0; kt < 8; ++kt) {
      wzR[kt] = *(const bf16x8*)(wzr + (kt * 16 + w) * 512 + l * 8);
      wrR[kt] = *(const bf16x8*)(wzr + (kt * 16 + 8 + w) * 512 + l * 8);
      whR[kt] = *(const bf16x8*)(wh_ + (kt * 8 + w) * 512 + l * 8);
    }
  }

  const float zb = p[pn + OFF_ZB + cw];
  const float rb = p[pn + OFF_RB + cw];
  const float hb = p[pn + OFF_HB + cw];
  const float gb = p[pn + OFF_GHB + cw];

  // LDS coords for this lane's h column (global k = 64 + cw)
  const int hkt = (64 + cw) >> 5;                       // 2..5
  const int hlane_base = (((64 + cw) >> 3) & 3) * 16;
  const int hj = cw & 7;

  // phase-A mapping: thread -> (row 0..31, 4-wide i block)
  const int arow = tid >> 4;          // 0..31
  const int ai0 = (tid & 15) * 4;     // 0..60
  const int amt = arow >> 4;
  const int akt = ai0 >> 5;
  const int alane = ((ai0 >> 3) & 3) * 16 + (arow & 15);
  const int aj = ai0 & 7;             // 0 or 4
  const float* __restrict__ Xp  = X  + (long)(b0 + arow) * TT * II + ai0;
  const float* __restrict__ XLp = XL + (long)(b0 + arow) * TT * II + ai0;
  const float* __restrict__ MKp = MK + ((long)(n * BATCH + b0 + arow) * TT) * II + ai0;
  const float* __restrict__ DEp = DE + ((long)(n * BATCH + b0 + arow) * TT) * II + ai0;
  float gxd4[4], gxb4[4];
#pragma unroll
  for (int u = 0; u < 4; ++u) {
    gxd4[u] = p[pn + OFF_GXW + (ai0 + u) * 65];
    gxb4[u] = p[pn + OFF_GXB + ai0 + u];
  }

  float h[2][4] = {{0.f, 0.f, 0.f, 0.f}, {0.f, 0.f, 0.f, 0.f}};

  // prefetch t=0 inputs (f32x4 = 16B lane loads)
  f32x4 fx  = *(const f32x4*)Xp;
  f32x4 fxl = *(const f32x4*)XLp;
  f32x4 fxm = *(const f32x4*)(XM + ai0);
  f32x4 fm  = __builtin_nontemporal_load((const f32x4*)MKp);
  f32x4 fd  = __builtin_nontemporal_load((const f32x4*)DEp);

  for (int t = 0; t < TT; ++t) {
    // ---- Phase A: elementwise x; write LDS A-frags ----
    {
      bf16x4 xh, xl_, mh, dh_, dl_;
#pragma unroll
      for (int u = 0; u < 4; ++u) {
        float m = fm[u], d = fd[u];
        float dx = __expf(-fmaxf(fmaf(d, gxd4[u], gxb4[u]), 0.f));
        float xv = m * fx[u] + (1.f - m) * (dx * fxl[u] + (1.f - dx) * fxm[u]);
        __bf16 vh = (__bf16)xv;
        xh[u] = vh; xl_[u] = (__bf16)(xv - (float)vh);
        mh[u] = (__bf16)m;
        __bf16 dvh = (__bf16)d;
        dh_[u] = dvh; dl_[u] = (__bf16)(d - (float)dvh);
      }
      *(bf16x4*)&combA_hi[amt][akt][alane][aj] = xh;
      *(bf16x4*)&combA_lo[amt][akt][alane][aj] = xl_;
      *(bf16x4*)&combA_hi[amt][6 + akt][alane][aj] = mh;
      *(bf16x4*)&dls_hi[amt][akt][alane][aj] = dh_;
      *(bf16x4*)&dls_lo[amt][akt][alane][aj] = dl_;
    }
    __syncthreads();

    // ---- Phase B: prefetch t+1; delta_h MFMA; h *= exp(-relu); h -> comb ----
    {
      const long to = (long)(t + 1 < TT ? t + 1 : t) * II;
      fx  = *(const f32x4*)(Xp + to);
      fxl = *(const f32x4*)(XLp + to);
      fxm = *(const f32x4*)(XM + to + ai0);
      fm  = __builtin_nontemporal_load((const f32x4*)(MKp + to));
      fd  = __builtin_nontemporal_load((const f32x4*)(DEp + to));

#pragma unroll
      for (int mt = 0; mt < 2; ++mt) {
        f32x4 ad = {0.f, 0.f, 0.f, 0.f};
#pragma unroll
        for (int kt = 0; kt < 2; ++kt) {
          bf16x8 ah = *(const bf16x8*)&dls_hi[mt][kt][l][0];
          bf16x8 al = *(const bf16x8*)&dls_lo[mt][kt][l][0];
          ad = mfma16(ah, wgR[kt], ad); ad = mfma16(al, wgR[kt], ad);
        }
#pragma unroll
        for (int r = 0; r < 4; ++r) {
          h[mt][r] *= __expf(-fmaxf(ad[r] + gb, 0.f));
          int lane = hlane_base + lg * 4 + r;
          __bf16 v = (__bf16)h[mt][r];
          combA_hi[mt][hkt][lane][hj] = v;
          combA_lo[mt][hkt][lane][hj] = (__bf16)(h[mt][r] - (float)v);
        }
      }
    }
    __syncthreads();

    // ---- Phase C: z,r MFMA; write r*h to rhA ----
    float zv[2][4];
#pragma unroll
    for (int mt = 0; mt < 2; ++mt) {
      f32x4 az = {0.f, 0.f, 0.f, 0.f}, ar = {0.f, 0.f, 0.f, 0.f};
#pragma unroll
      for (int kt = 0; kt < 8; ++kt) {
        bf16x8 ah = *(const bf16x8*)&combA_hi[mt][kt][l][0];
        az = mfma16(ah, wzR[kt], az);
        ar = mfma16(ah, wrR[kt], ar);
        if (kt < 6) {  // mask region lo == 0
          bf16x8 al = *(const bf16x8*)&combA_lo[mt][kt][l][0];
          az = mfma16(al, wzR[kt], az);
          ar = mfma16(al, wrR[kt], ar);
        }
      }
#pragma unroll
      for (int r = 0; r < 4; ++r) {
        zv[mt][r] = sigmoidf_(az[r] + zb);
        float rv = sigmoidf_(ar[r] + rb);
        float rh = rv * h[mt][r];
        int lane = hlane_base + lg * 4 + r;
        __bf16 v = (__bf16)rh;
        rhA_hi[mt][hkt - 2][lane][hj] = v;
        rhA_lo[mt][hkt - 2][lane][hj] = (__bf16)(rh - (float)v);
      }
    }
    __syncthreads();

    // ---- Phase D: h_tilde MFMA; h update ----
#pragma unroll
    for (int mt = 0; mt < 2; ++mt) {
      f32x4 ahh = {0.f, 0.f, 0.f, 0.f};
#pragma unroll
      for (int kt = 0; kt < 8; ++kt) {
        bf16x8 ah, al;
        bool has_lo = true;
        if (kt < 2)      { ah = *(const bf16x8*)&combA_hi[mt][kt][l][0];
                           al = *(const bf16x8*)&combA_lo[mt][kt][l][0]; }
        else if (kt < 6) { ah = *(const bf16x8*)&rhA_hi[mt][kt - 2][l][0];
                           al = *(const bf16x8*)&rhA_lo[mt][kt - 2][l][0]; }
        else             { ah = *(const bf16x8*)&combA_hi[mt][kt][l][0];
                           has_lo = false; }
        ahh = mfma16(ah, whR[kt], ahh);
        if (has_lo) ahh = mfma16(al, whR[kt], ahh);
      }
#pragma unroll
      for (int r = 0; r < 4; ++r) {
        float ht = tanhf(ahh[r] + hb);
        h[mt][r] = (1.f - zv[mt][r]) * h[mt][r] + zv[mt][r] * ht;
      }
    }
    __syncthreads();
  }

  // ---- fc epilogue ----
#pragma unroll
  for (int mt = 0; mt < 2; ++mt)
#pragma unroll
    for (int r = 0; r < 4; ++r) hstage[mt * 16 + lg * 4 + r][cw] = h[mt][r];
  __syncthreads();
  if (tid < BB) {
    float acc = p[pn + OFF_FCB];
    for (int j = 0; j < HH; ++j) acc = fmaf(hstage[tid][j], p[pn + OFF_FCW + j], acc);
    out[n * BATCH + b0 + tid] = sigmoidf_(acc);
  }
}

extern "C" void kernel_launch(void* const* d_in, const int* in_sizes, int n_in,
                              void* d_out, int out_size, void* d_ws, size_t ws_size,
                              hipStream_t stream) {
  const float* p  = (const float*)d_in[0];
  const float* X  = (const float*)d_in[1];
  const float* XL = (const float*)d_in[2];
  const float* XM = (const float*)d_in[3];
  const float* MK = (const float*)d_in[4];
  const float* DE = (const float*)d_in[5];
  float* out = (float*)d_out;
  __bf16* ws = (__bf16*)d_ws;
  if (ws_size < (size_t)WS_ELEMS * 2) return;

  hipLaunchKernelGGL(repack_kernel, dim3(4096), dim3(256), 0, stream, p, ws);
  hipLaunchKernelGGL(grud_main, dim3(NF * (BATCH / BB)), dim3(NTHR), 0, stream,
                     p, X, XL, XM, MK, DE, ws, out);
}